// Round 11
// baseline (66.998 us; speedup 1.0000x reference)
//
#include <hip/hip_runtime.h>

typedef __bf16 v8bf __attribute__((ext_vector_type(8)));
typedef float f32x4 __attribute__((ext_vector_type(4)));

#define C_IN 256
#define HW   64
#define OHW  63
#define NOC  128

// Wf: [kp(4)][khkw(4)][cblk(32)][oc(128)][j(8)] bf16, 1 MiB. Coalesced.
__global__ void wprep(const float* __restrict__ w, __bf16* __restrict__ Wf) {
  int f = blockIdx.x;                 // 512 filters
  int c = threadIdx.x;                // 256 channels
  f32x4 v = *(const f32x4*)(w + (size_t)f * 1024 + c * 4);  // 4 khkw taps
  int oc = f >> 2, kp = f & 3;
#pragma unroll
  for (int khkw = 0; khkw < 4; ++khkw)
    Wf[(((size_t)(kp * 4 + khkw) * 32 + (c >> 3)) * 128 + oc) * 8 + (c & 7)] =
        (__bf16)v[khkw];
}

// MEASUREMENT ROUND: exact R5 kernel, but the chunk loop runs TWICE
// (16 iters over q&7) and the epilogue halves acc. T - 44.65 = loop cost.
__global__ __launch_bounds__(1024, 4) void robin_main(
    const float* __restrict__ x, const __bf16* __restrict__ Wf,
    const float* __restrict__ bias, float* __restrict__ out) {
  __shared__ __align__(16) __bf16 xs[2][5 * 33 * 64];   // 2 x 21120 B
  char* xb0 = (char*)xs[0];
  char* xb1 = (char*)xs[1];

  const int tid  = threadIdx.x;
  const int lane = tid & 63;
  const int wid  = tid >> 6;
  const int hb   = blockIdx.x;       // 16
  const int n    = blockIdx.y;       // 16
  const int h0   = hb * 4;

  const int ocg  = wid >> 2;         // 0..3 -> 32 oc each
  const int kp   = wid & 3;          // parity class
  const int ph   = kp >> 1, pw = kp & 1;
  const int lcol = lane & 15;        // pixel col (B) / oc row (A)
  const int lg   = lane >> 4;        // k-octet group

  // zero-fill wpair=32 pad rows (wcol 64/65), both buffers
  if (tid < 80) {
    int g  = tid & 7;
    int t2 = tid >> 3;
    int dy = t2 % 5, bi = t2 / 5;
    f32x4 z = {0.f, 0.f, 0.f, 0.f};
    *(f32x4*)((bi ? xb1 : xb0) + (dy * 33 + 32) * 128 + g * 16) = z;
  }

  // chunk-invariant B-frag base offsets (r -> +8448, hh -> +2048; deltas
  // don't touch swizzled bits 4..6)
  int boff[4];
#pragma unroll
  for (int khkw = 0; khkw < 4; ++khkw) {
    int kh = khkw >> 1, kw = khkw & 1;
    int dy0  = ph + kh;
    int wcol = 2 * lcol + pw + kw;
    int wp_  = wcol >> 1;
    boff[khkw] = ((dy0 * 33 + wp_) * 128 + (wcol & 1) * 64 + lg * 16) ^
                 ((wp_ & 7) << 4);
  }

  f32x4 acc[2][4];
#pragma unroll
  for (int m = 0; m < 2; ++m)
#pragma unroll
    for (int f = 0; f < 4; ++f) acc[m][f] = (f32x4){0.f, 0.f, 0.f, 0.f};

  const float* xbase = x + (size_t)n * C_IN * HW * HW;
  f32x4 xr[3];
  v8bf  a_reg[4][2];

#define A_LOAD(QQ)                                                             \
  {                                                                            \
    _Pragma("unroll") for (int khkw = 0; khkw < 4; ++khkw) {                   \
      const __bf16* wp =                                                       \
          Wf + (((size_t)(kp * 4 + khkw) * 32 + (QQ) * 4 + lg) * 128 +        \
                ocg * 32 + lcol) * 8;                                          \
      a_reg[khkw][0] = *(const v8bf*)wp;                                       \
      a_reg[khkw][1] = *(const v8bf*)(wp + 128);                               \
    }                                                                          \
  }

  // 2560 float4 units per chunk: unit v -> dy=v>>9, c=(v>>4)&31, w4=v&15
#define LOADQ(QQ)                                                              \
  {                                                                            \
    const int cbase = (QQ) * 32;                                               \
    _Pragma("unroll") for (int k = 0; k < 3; ++k) {                            \
      int v = k * 1024 + tid;                                                  \
      if (v < 2560) {                                                          \
        int w4 = v & 15, c = (v >> 4) & 31, dy = v >> 9;                       \
        int y = h0 + dy;                                                       \
        if (y < HW)                                                            \
          xr[k] = *(const f32x4*)(xbase + ((size_t)(cbase + c) * HW + y) * HW +\
                                  w4 * 4);                                     \
        else                                                                   \
          xr[k] = (f32x4){0.f, 0.f, 0.f, 0.f};                                 \
      }                                                                        \
    }                                                                          \
  }

#define WRITEQ(QQ)                                                             \
  {                                                                            \
    char* xd = ((QQ) & 1) ? xb1 : xb0;                                         \
    _Pragma("unroll") for (int k = 0; k < 3; ++k) {                            \
      int v = k * 1024 + tid;                                                  \
      if (v < 2560) {                                                          \
        int w4 = v & 15, c = (v >> 4) & 31, dy = v >> 9;                       \
        _Pragma("unroll") for (int j = 0; j < 4; ++j) {                        \
          int wcol = w4 * 4 + j;                                               \
          int wp_  = wcol >> 1;                                                \
          int bo = ((dy * 33 + wp_) * 128 + (wcol & 1) * 64 + c * 2) ^         \
                   ((wp_ & 7) << 4);                                           \
          *(__bf16*)(xd + bo) = (__bf16)xr[k][j];                              \
        }                                                                      \
      }                                                                        \
    }                                                                          \
  }

  // prologue: fill buffer 0 with chunk 0
  LOADQ(0);
  WRITEQ(0);
  __syncthreads();

  // 16 iterations over chunk q&7 (two full passes; acc = 2x true sum).
  // Buffer parity: chunk (q&7) & 1 == q & 1, so the dbuf mapping is
  // identical to the single-pass version at every step.
  for (int q = 0; q < 16; ++q) {
    const int cq = q & 7;
    A_LOAD(cq);                        // issued FIRST (vmcnt FIFO)
    if (q < 15) LOADQ((q + 1) & 7);    // x prefetch stays in flight

    // ---- compute chunk cq: 4 khkw K-steps x 8 MFMA, zero VMEM inside ----
    {
      const char* xsb = (cq & 1) ? xb1 : xb0;
#pragma unroll
      for (int khkw = 0; khkw < 4; ++khkw) {
        v8bf b[4];
#pragma unroll
        for (int r = 0; r < 2; ++r)
#pragma unroll
          for (int hh = 0; hh < 2; ++hh)
            b[r * 2 + hh] =
                *(const v8bf*)(xsb + boff[khkw] + r * 8448 + hh * 2048);

#pragma unroll
        for (int m = 0; m < 2; ++m)
#pragma unroll
          for (int f = 0; f < 4; ++f)
            acc[m][f] = __builtin_amdgcn_mfma_f32_16x16x32_bf16(
                a_reg[khkw][m], b[f], acc[m][f], 0, 0, 0);
      }
    }

    if (q < 15) {
      WRITEQ((q + 1) & 7);   // other buffer, free since compute(q-1)
      __syncthreads();       // writes visible before compute(q+1)
    }
  }

  // ---- epilogue: halve (loop ran 2x). D col=lane&15, row=(lane>>4)*4+reg --
#pragma unroll
  for (int m = 0; m < 2; ++m) {
#pragma unroll
    for (int r = 0; r < 2; ++r) {
      const int h = h0 + 2 * r + ph;
#pragma unroll
      for (int hh = 0; hh < 2; ++hh) {
        const int w = 2 * (hh * 16 + lcol) + pw;
        f32x4 v = acc[m][r * 2 + hh];
        if (h < OHW && w < OHW) {
#pragma unroll
          for (int reg = 0; reg < 4; ++reg) {
            int oc = ocg * 32 + m * 16 + lg * 4 + reg;
            out[((size_t)(n * NOC + oc) * OHW + h) * OHW + w] =
                v[reg] * 0.5f + bias[oc * 4 + kp];
          }
        }
      }
    }
  }
#undef A_LOAD
#undef LOADQ
#undef WRITEQ
}

extern "C" void kernel_launch(void* const* d_in, const int* in_sizes, int n_in,
                              void* d_out, int out_size, void* d_ws, size_t ws_size,
                              hipStream_t stream) {
  const float* x      = (const float*)d_in[0];
  const float* weight = (const float*)d_in[1];
  const float* bias   = (const float*)d_in[2];
  float* out          = (float*)d_out;
  __bf16* Wf          = (__bf16*)d_ws;   // 1 MiB fragment-ordered weights

  wprep<<<512, 256, 0, stream>>>(weight, Wf);
  robin_main<<<dim3(16, 16), 1024, 0, stream>>>(x, Wf, bias, out);
}

// Round 12
// 42.754 us; speedup vs baseline: 1.5671x; 1.5671x over previous
//
#include <hip/hip_runtime.h>

typedef __bf16 v8bf __attribute__((ext_vector_type(8)));
typedef float f32x4 __attribute__((ext_vector_type(4)));

#define C_IN 256
#define HW   64
#define OHW  63
#define NOC  128

// Wf: [kp(4)][khkw(4)][cblk(32)][oc(128)][j(8)] bf16, 1 MiB. Coalesced.
__global__ void wprep(const float* __restrict__ w, __bf16* __restrict__ Wf) {
  int f = blockIdx.x;                 // 512 filters
  int c = threadIdx.x;                // 256 channels
  f32x4 v = *(const f32x4*)(w + (size_t)f * 1024 + c * 4);  // 4 khkw taps
  int oc = f >> 2, kp = f & 3;
#pragma unroll
  for (int khkw = 0; khkw < 4; ++khkw)
    Wf[(((size_t)(kp * 4 + khkw) * 32 + (c >> 3)) * 128 + oc) * 8 + (c & 7)] =
        (__bf16)v[khkw];
}

// R5 structure (44.65us) + LDS-transposed epilogue for stride-1 stores.
// Block: n x 4 out rows x 128 oc, 1024 thr (16 waves, 4/SIMD).
// wave = ocg(4: 32 oc) x kp(4). LDS loop tile: [dy(5)][wpair(33)][par(2)][c(32)]
// bf16, XOR-swizzled, dbuf; reused post-loop as [oc(128)][68] f32 for epilogue.
__global__ __launch_bounds__(1024, 4) void robin_main(
    const float* __restrict__ x, const __bf16* __restrict__ Wf,
    const float* __restrict__ bias, float* __restrict__ out) {
  __shared__ __align__(16) char smem[42240];       // 2x21120 loop / 34816 epi
  char* xb0 = smem;
  char* xb1 = smem + 21120;

  const int tid  = threadIdx.x;
  const int lane = tid & 63;
  const int wid  = tid >> 6;
  const int hb   = blockIdx.x;       // 16
  const int n    = blockIdx.y;       // 16
  const int h0   = hb * 4;

  const int ocg  = wid >> 2;         // 0..3 -> 32 oc each
  const int kp   = wid & 3;          // parity class
  const int ph   = kp >> 1, pw = kp & 1;
  const int lcol = lane & 15;        // pixel col (B) / oc row (A)
  const int lg   = lane >> 4;        // k-octet group

  // zero-fill wpair=32 pad rows (wcol 64/65), both buffers
  if (tid < 80) {
    int g  = tid & 7;
    int t2 = tid >> 3;
    int dy = t2 % 5, bi = t2 / 5;
    f32x4 z = {0.f, 0.f, 0.f, 0.f};
    *(f32x4*)((bi ? xb1 : xb0) + (dy * 33 + 32) * 128 + g * 16) = z;
  }

  // chunk-invariant B-frag base offsets (r -> +8448, hh -> +2048; deltas
  // don't touch swizzled bits 4..6)
  int boff[4];
#pragma unroll
  for (int khkw = 0; khkw < 4; ++khkw) {
    int kh = khkw >> 1, kw = khkw & 1;
    int dy0  = ph + kh;
    int wcol = 2 * lcol + pw + kw;
    int wp_  = wcol >> 1;
    boff[khkw] = ((dy0 * 33 + wp_) * 128 + (wcol & 1) * 64 + lg * 16) ^
                 ((wp_ & 7) << 4);
  }

  f32x4 acc[2][4];
#pragma unroll
  for (int m = 0; m < 2; ++m)
#pragma unroll
    for (int f = 0; f < 4; ++f) acc[m][f] = (f32x4){0.f, 0.f, 0.f, 0.f};

  const float* xbase = x + (size_t)n * C_IN * HW * HW;
  f32x4 xr[3];
  v8bf  a_reg[4][2];

#define A_LOAD(QQ)                                                             \
  {                                                                            \
    _Pragma("unroll") for (int khkw = 0; khkw < 4; ++khkw) {                   \
      const __bf16* wp =                                                       \
          Wf + (((size_t)(kp * 4 + khkw) * 32 + (QQ) * 4 + lg) * 128 +        \
                ocg * 32 + lcol) * 8;                                          \
      a_reg[khkw][0] = *(const v8bf*)wp;                                       \
      a_reg[khkw][1] = *(const v8bf*)(wp + 128);                               \
    }                                                                          \
  }

  // 2560 float4 units per chunk: unit v -> dy=v>>9, c=(v>>4)&31, w4=v&15
#define LOADQ(QQ)                                                              \
  {                                                                            \
    const int cbase = (QQ) * 32;                                               \
    _Pragma("unroll") for (int k = 0; k < 3; ++k) {                            \
      int v = k * 1024 + tid;                                                  \
      if (v < 2560) {                                                          \
        int w4 = v & 15, c = (v >> 4) & 31, dy = v >> 9;                       \
        int y = h0 + dy;                                                       \
        if (y < HW)                                                            \
          xr[k] = *(const f32x4*)(xbase + ((size_t)(cbase + c) * HW + y) * HW +\
                                  w4 * 4);                                     \
        else                                                                   \
          xr[k] = (f32x4){0.f, 0.f, 0.f, 0.f};                                 \
      }                                                                        \
    }                                                                          \
  }

#define WRITEQ(QQ)                                                             \
  {                                                                            \
    char* xd = ((QQ) & 1) ? xb1 : xb0;                                         \
    _Pragma("unroll") for (int k = 0; k < 3; ++k) {                            \
      int v = k * 1024 + tid;                                                  \
      if (v < 2560) {                                                          \
        int w4 = v & 15, c = (v >> 4) & 31, dy = v >> 9;                       \
        _Pragma("unroll") for (int j = 0; j < 4; ++j) {                        \
          int wcol = w4 * 4 + j;                                               \
          int wp_  = wcol >> 1;                                                \
          int bo = ((dy * 33 + wp_) * 128 + (wcol & 1) * 64 + c * 2) ^         \
                   ((wp_ & 7) << 4);                                           \
          *(__bf16*)(xd + bo) = (__bf16)xr[k][j];                              \
        }                                                                      \
      }                                                                        \
    }                                                                          \
  }

  // prologue: fill buffer 0 with chunk 0
  LOADQ(0);
  WRITEQ(0);
  __syncthreads();

  for (int q = 0; q < 8; ++q) {
    A_LOAD(q);                // issued FIRST (vmcnt FIFO: keep x in flight)
    if (q < 7) LOADQ(q + 1);

    // ---- compute chunk q: 4 khkw K-steps x 8 MFMA, zero VMEM inside ----
    {
      const char* xsb = (q & 1) ? xb1 : xb0;
#pragma unroll
      for (int khkw = 0; khkw < 4; ++khkw) {
        v8bf b[4];
#pragma unroll
        for (int r = 0; r < 2; ++r)
#pragma unroll
          for (int hh = 0; hh < 2; ++hh)
            b[r * 2 + hh] =
                *(const v8bf*)(xsb + boff[khkw] + r * 8448 + hh * 2048);

#pragma unroll
        for (int m = 0; m < 2; ++m)
#pragma unroll
          for (int f = 0; f < 4; ++f)
            acc[m][f] = __builtin_amdgcn_mfma_f32_16x16x32_bf16(
                a_reg[khkw][m], b[f], acc[m][f], 0, 0, 0);
      }
    }

    if (q < 7) {
      WRITEQ(q + 1);     // other buffer, free since compute(q-1)
      __syncthreads();   // writes visible before compute(q+1)
    }
  }

  // ---- epilogue: LDS transpose -> stride-1 coalesced scalar stores ----
  // acc D layout: col=lane&15 (pixel), row=(lane>>4)*4+reg (oc).
  float bv[2][4];
#pragma unroll
  for (int m = 0; m < 2; ++m)
#pragma unroll
    for (int reg = 0; reg < 4; ++reg)
      bv[m][reg] = bias[(ocg * 32 + m * 16 + lg * 4 + reg) * 4 + kp];

  float* eb = (float*)smem;          // [oc(128)][68] f32 = 34816 B
#pragma unroll
  for (int p = 0; p < 4; ++p) {
    const int h = h0 + p;
    __syncthreads();                 // prev pass reads / loop reads done
    if ((ph == (p & 1)) && h < OHW) {
      const int rsel = p >> 1;
#pragma unroll
      for (int m = 0; m < 2; ++m)
#pragma unroll
        for (int hh = 0; hh < 2; ++hh) {
          f32x4 v = acc[m][rsel * 2 + hh];
          int w = 2 * (hh * 16 + lcol) + pw;       // <= 63
#pragma unroll
          for (int reg = 0; reg < 4; ++reg)
            eb[(ocg * 32 + m * 16 + lg * 4 + reg) * 68 + w] =
                v[reg] + bv[m][reg];
        }
    }
    __syncthreads();                 // tile complete
    if (h < OHW) {
      const int lc2 = tid & 15;
#pragma unroll
      for (int s = 0; s < 2; ++s) {
        int oc = (tid >> 4) + (s << 6);
        float* orow = out + ((size_t)(n * NOC + oc) * OHW + h) * OHW;
        const float* erow = eb + oc * 68;
#pragma unroll
        for (int b = 0; b < 4; ++b) {
          int w = lc2 + 16 * b;
          if (w < OHW) orow[w] = erow[w];
        }
      }
    }
  }
#undef A_LOAD
#undef LOADQ
#undef WRITEQ
}

extern "C" void kernel_launch(void* const* d_in, const int* in_sizes, int n_in,
                              void* d_out, int out_size, void* d_ws, size_t ws_size,
                              hipStream_t stream) {
  const float* x      = (const float*)d_in[0];
  const float* weight = (const float*)d_in[1];
  const float* bias   = (const float*)d_in[2];
  float* out          = (float*)d_out;
  __bf16* Wf          = (__bf16*)d_ws;   // 1 MiB fragment-ordered weights

  wprep<<<512, 256, 0, stream>>>(weight, Wf);
  robin_main<<<dim3(16, 16), 1024, 0, stream>>>(x, Wf, bias, out);
}